// Round 1
// baseline (93.334 us; speedup 1.0000x reference)
//
#include <hip/hip_runtime.h>

// ---------------------------------------------------------------------------
// LaplaceKAN layer as a fused-feature bf16 MFMA GEMM.
//   y[b,o] = sum_{i,g} exp(-x[b,i]*lam_g)*C[0,o,i,g] + exp(+x[b,i]*lam_g)*C[1,o,i,g] + bias[o]
//   lam_g = 0.1 + 0.06*g, g in [0,16)
// GEMM view: M=4096, N=256, K=8192 (k = s*4096 + i*16 + g), A generated on the
// fly from x via p*r^g recurrence (2 exp + 15 mul per 16 features), B = coeffs
// pre-cast to bf16 in workspace with natural [o][k] (B^T) layout.
// Tiling: BM=128, BN=128, BK=64, 256 threads (2x2 waves of 64x64), splitK=8
// -> 512 blocks = 2 blocks/CU so gen-VALU overlaps MFMA across waves.
// ---------------------------------------------------------------------------

typedef __bf16 bf16x8 __attribute__((ext_vector_type(8)));
typedef __bf16 bf16x4 __attribute__((ext_vector_type(4)));
typedef float  f32x4  __attribute__((ext_vector_type(4)));

#define M_TOT 4096
#define N_TOT 256
#define MN_TOT (M_TOT * N_TOT)
#define SPLITK 8

__device__ __forceinline__ void gload_lds16(const __bf16* g, __bf16* l) {
  // async 16B/lane global->LDS; LDS dest = wave-uniform base + lane*16
  __builtin_amdgcn_global_load_lds(
      (const __attribute__((address_space(1))) void*)g,
      (__attribute__((address_space(3))) void*)l, 16, 0, 0);
}

// fp32 coeffs (2,O,I,G) -> bf16 Wb[o][k], k = s*4096 + i*16 + g.
// Both sides contiguous over x=(i*16+g) for fixed (s,o): pure chunk copy+cvt.
__global__ void convert_w(const float* __restrict__ C, __bf16* __restrict__ W) {
  int t = blockIdx.x * 256 + threadIdx.x;      // 524288 threads, 4 elems each
  int E = t << 2;
  int c = E >> 12, x4 = E & 4095;              // c = s*256+o
  int s = c >> 8, o = c & 255;
  const f32x4 v = *(const f32x4*)(C + (size_t)c * 4096 + x4);
  bf16x4 w;
  w[0] = (__bf16)v[0]; w[1] = (__bf16)v[1]; w[2] = (__bf16)v[2]; w[3] = (__bf16)v[3];
  *(bf16x4*)(W + (size_t)o * 8192 + (size_t)s * 4096 + x4) = w;
}

// MODE 0: write split-K partials to P.  MODE 1: atomicAdd into Out (+bias at kt==0).
template <int MODE>
__global__ __launch_bounds__(256, 2)
void laplace_gemm(const float* __restrict__ X, const __bf16* __restrict__ Wb,
                  const float* __restrict__ Bias, float* __restrict__ Out,
                  float* __restrict__ P) {
  // A tile padded to 72 elem/row (144B: 16B-aligned, bank-balanced reads/writes)
  __shared__ __bf16 As[128 * 72];
  // B tile 128x64, rows 128B; 16B chunks XOR-swizzled by (row&7) for bank spread
  __shared__ __bf16 Bs[128 * 64];

  const int tid = threadIdx.x;
  const int mt = blockIdx.x, nt = blockIdx.y, kt = blockIdx.z;
  const int m0 = mt * 128, n0 = nt * 128;
  const int s   = kt >> 2;          // sign half: 0 -> exp(-e), 1 -> exp(+e)
  const int i0c = (kt & 3) * 64;    // i-range of this K-chunk (64 i values)

  const int wv = tid >> 6, lane = tid & 63;
  const int wm = wv & 1, wn = wv >> 1;    // 2x2 wave grid, each 64x64
  const int lm = lane & 15, q = lane >> 4;

  // feature-gen assignment: thread handles two (row, i-sub) pairs per iter
  const int mr0 = tid >> 2,         ii0 = tid & 3;
  const int mr1 = (256 + tid) >> 2, ii1 = tid & 3;   // (256+tid)&3 == tid&3
  const float* xp0 = X + (size_t)(m0 + mr0) * 256 + i0c + ii0;
  const float* xp1 = X + (size_t)(m0 + mr1) * 256 + i0c + ii1;

  const float sgn = s ? 1.0f : -1.0f;
  const float c0 = 0.1f * sgn, cd = 0.06f * sgn;

  const f32x4 zero = {0.f, 0.f, 0.f, 0.f};
  f32x4 acc[4][4];
#pragma unroll
  for (int a = 0; a < 4; ++a)
#pragma unroll
    for (int b = 0; b < 4; ++b) acc[a][b] = zero;

  // element offset of this K-chunk within a Wb row
  const size_t wrow = (size_t)s * 4096 + (size_t)i0c * 16;

  float xc0 = *xp0, xc1 = *xp1;

  for (int j = 0; j < 16; ++j) {   // 16 x BK=64 -> K-chunk 1024
    // ---- async stage B tile (4 x 16B per thread) ----
    const size_t kw = wrow + (size_t)j * 64;
#pragma unroll
    for (int qq = 0; qq < 4; ++qq) {
      const int idx = qq * 256 + tid;
      const int r = idx >> 3, cc = idx & 7;
      const __bf16* gsrc = Wb + (size_t)(n0 + r) * 8192 + kw + ((cc ^ (r & 7)) << 3);
      __bf16* ldst = Bs + ((qq * 256 + (tid & ~63)) << 3);  // wave-uniform base
      gload_lds16(gsrc, ldst);
    }

    // prefetch next iter's x while loads are in flight
    float xn0 = 0.f, xn1 = 0.f;
    if (j < 15) { xn0 = xp0[4 * (j + 1)]; xn1 = xp1[4 * (j + 1)]; }

    // ---- generate A features: f_g = p * r^g ----
    {
      const float p0 = __expf(c0 * xc0), rr = __expf(cd * xc0);
      bf16x8 v0, v1; float f = p0;
#pragma unroll
      for (int h = 0; h < 8; ++h) { v0[h] = (__bf16)f; f *= rr; }
#pragma unroll
      for (int h = 0; h < 8; ++h) { v1[h] = (__bf16)f; f *= rr; }
      *(bf16x8*)&As[mr0 * 72 + ii0 * 16]     = v0;
      *(bf16x8*)&As[mr0 * 72 + ii0 * 16 + 8] = v1;
    }
    {
      const float p0 = __expf(c0 * xc1), rr = __expf(cd * xc1);
      bf16x8 v0, v1; float f = p0;
#pragma unroll
      for (int h = 0; h < 8; ++h) { v0[h] = (__bf16)f; f *= rr; }
#pragma unroll
      for (int h = 0; h < 8; ++h) { v1[h] = (__bf16)f; f *= rr; }
      *(bf16x8*)&As[mr1 * 72 + ii1 * 16]     = v0;
      *(bf16x8*)&As[mr1 * 72 + ii1 * 16 + 8] = v1;
    }

    __syncthreads();   // drains vmcnt (B tile) + lgkm (A writes)

    // ---- MFMA: 2 k-steps x 4x4 frags ----
#pragma unroll
    for (int kk = 0; kk < 2; ++kk) {
      bf16x8 af[4], bf[4];
#pragma unroll
      for (int a = 0; a < 4; ++a)
        af[a] = *(const bf16x8*)&As[(wm * 64 + a * 16 + lm) * 72 + kk * 32 + q * 8];
      const int pc8 = (((kk << 2) + q) ^ (lm & 7)) << 3;  // un-swizzle B chunk
#pragma unroll
      for (int b = 0; b < 4; ++b)
        bf[b] = *(const bf16x8*)&Bs[(wn * 64 + b * 16 + lm) * 64 + pc8];
#pragma unroll
      for (int a = 0; a < 4; ++a)
#pragma unroll
        for (int b = 0; b < 4; ++b)
          acc[a][b] = __builtin_amdgcn_mfma_f32_16x16x32_bf16(af[a], bf[b], acc[a][b], 0, 0, 0);
    }
    __syncthreads();   // before next iter overwrites tiles

    xc0 = xn0; xc1 = xn1;
  }

  // ---- epilogue: D[row=q*4+reg][col=lm] (m89-verified C/D layout) ----
  if constexpr (MODE == 0) {
    float* Pk = P + (size_t)kt * MN_TOT;
#pragma unroll
    for (int a = 0; a < 4; ++a) {
      const int mrow = m0 + wm * 64 + a * 16 + q * 4;
#pragma unroll
      for (int rr = 0; rr < 4; ++rr)
#pragma unroll
        for (int b = 0; b < 4; ++b) {
          const int n = n0 + wn * 64 + b * 16 + lm;
          Pk[(size_t)(mrow + rr) * 256 + n] = acc[a][b][rr];
        }
    }
  } else {
#pragma unroll
    for (int a = 0; a < 4; ++a) {
      const int mrow = m0 + wm * 64 + a * 16 + q * 4;
#pragma unroll
      for (int rr = 0; rr < 4; ++rr)
#pragma unroll
        for (int b = 0; b < 4; ++b) {
          const int n = n0 + wn * 64 + b * 16 + lm;
          float v = acc[a][b][rr];
          if (kt == 0) v += Bias[n];
          atomicAdd(&Out[(size_t)(mrow + rr) * 256 + n], v);
        }
    }
  }
}

// sum 8 split-K partials + bias -> out
__global__ void reduce_bias(const float* __restrict__ P, const float* __restrict__ Bias,
                            float* __restrict__ Out) {
  const int t = blockIdx.x * 256 + threadIdx.x;
  const size_t base = (size_t)t * 4;
  f32x4 sv = *(const f32x4*)&P[base];
#pragma unroll
  for (int k = 1; k < SPLITK; ++k) sv += *(const f32x4*)&P[(size_t)k * MN_TOT + base];
  sv += *(const f32x4*)&Bias[base & 255];
  *(f32x4*)&Out[base] = sv;
}

extern "C" void kernel_launch(void* const* d_in, const int* in_sizes, int n_in,
                              void* d_out, int out_size, void* d_ws, size_t ws_size,
                              hipStream_t stream) {
  const float* X    = (const float*)d_in[0];
  const float* C    = (const float*)d_in[1];
  const float* Bias = (const float*)d_in[2];
  float* Out = (float*)d_out;

  __bf16* Wb = (__bf16*)d_ws;
  const size_t wb_bytes = (size_t)N_TOT * 8192 * sizeof(__bf16);   // 4 MiB
  const size_t p_bytes  = (size_t)SPLITK * MN_TOT * sizeof(float); // 32 MiB
  float* P = (float*)((char*)d_ws + wb_bytes);

  convert_w<<<2048, 256, 0, stream>>>(C, Wb);

  if (ws_size >= wb_bytes + p_bytes) {
    laplace_gemm<0><<<dim3(32, 2, SPLITK), 256, 0, stream>>>(X, Wb, Bias, Out, P);
    reduce_bias<<<1024, 256, 0, stream>>>(P, Bias, Out);
  } else {
    hipMemsetAsync(d_out, 0, (size_t)out_size * sizeof(float), stream);
    laplace_gemm<1><<<dim3(32, 2, SPLITK), 256, 0, stream>>>(X, Wb, Bias, Out, P);
  }
}